// Round 2
// baseline (1956.072 us; speedup 1.0000x reference)
//
#include <hip/hip_runtime.h>

#define TPB 256

// ---------------- fast tanh: (e^{2x}-1)/(e^{2x}+1), clamp avoids inf*0 ----------------
__device__ __forceinline__ float fast_tanh(float v) {
    float vc = fminf(v, 15.0f);                 // tanh(15) == 1.0f in fp32
    float e  = __expf(vc + vc);                 // v_exp_f32 path
    float r  = __builtin_amdgcn_rcpf(e + 1.0f); // v_rcp_f32, ~1e-7 rel err
    return (e - 1.0f) * r;
}

__device__ __forceinline__ void load64(float (&z)[64], const float* __restrict__ p) {
    const float4* p4 = (const float4*)p;
#pragma unroll
    for (int q = 0; q < 16; ++q) {
        float4 b = p4[q];
        z[4*q+0] = b.x; z[4*q+1] = b.y; z[4*q+2] = b.z; z[4*q+3] = b.w;
    }
}

__device__ __forceinline__ void zero64(float (&z)[64]) {
#pragma unroll
    for (int j = 0; j < 64; ++j) z[j] = 0.0f;
}

// z[0..63] += sum_k buf[k][tid] * W[k*64 + j]   (W rows contiguous, uniform -> s_loads)
__device__ __forceinline__ void mv64(float (&z)[64], const float* __restrict__ W,
                                     float (*buf)[TPB], int tid) {
#pragma unroll 2
    for (int k = 0; k < 64; ++k) {
        float ak = buf[k][tid];
        const float4* w4 = (const float4*)(W + (k << 6));
#pragma unroll
        for (int q = 0; q < 16; ++q) {
            float4 w = w4[q];
            z[4*q+0] = fmaf(ak, w.x, z[4*q+0]);
            z[4*q+1] = fmaf(ak, w.y, z[4*q+1]);
            z[4*q+2] = fmaf(ak, w.z, z[4*q+2]);
            z[4*q+3] = fmaf(ak, w.w, z[4*q+3]);
        }
    }
}

// coupling net: 2 -> 125 (relu) -> 125 (tanh) -> 2.  h1 recomputed on the fly (2 FMA each),
// layer2 done in two 64-wide halves (cols 125..127 zero-padded so they contribute 0).
__device__ __forceinline__ void coupling_net(float u0, float u1,
        const float* __restrict__ cw1, const float* __restrict__ cb1,
        const float* __restrict__ wsf, const float* __restrict__ cb3,
        float& o0, float& o1) {
    const float* cb2p = wsf + 16000;   // [128]
    const float* cw3p = wsf + 16128;   // [128][2]
    float a0 = cb3[0], a1 = cb3[1];
#pragma unroll 1
    for (int half = 0; half < 2; ++half) {
        float z[64];
        load64(z, cb2p + half * 64);
#pragma unroll 2
        for (int k = 0; k < 125; ++k) {
            float h = fmaf(u1, cw1[125 + k], fmaf(u0, cw1[k], cb1[k]));
            h = fmaxf(h, 0.0f);
            const float4* w4 = (const float4*)(wsf + k * 128 + half * 64); // cw2 padded [125][128]
#pragma unroll
            for (int q = 0; q < 16; ++q) {
                float4 w = w4[q];
                z[4*q+0] = fmaf(h, w.x, z[4*q+0]);
                z[4*q+1] = fmaf(h, w.y, z[4*q+1]);
                z[4*q+2] = fmaf(h, w.z, z[4*q+2]);
                z[4*q+3] = fmaf(h, w.w, z[4*q+3]);
            }
        }
#pragma unroll
        for (int j = 0; j < 64; ++j) {
            float t = fast_tanh(z[j]);
            int jj = (half << 6) + j;
            a0 = fmaf(t, cw3p[2*jj+0], a0);
            a1 = fmaf(t, cw3p[2*jj+1], a1);
        }
    }
    o0 = a0; o1 = a1;
}

// pack: ws = [ cw2p 125x128 | cb2p 128 | cw3p 128x2 | hw2T..hw5T 4x64x64 ]  (32768 floats)
__global__ void pack_weights(const float* __restrict__ cw2, const float* __restrict__ cb2,
                             const float* __restrict__ cw3,
                             const float* __restrict__ hw2, const float* __restrict__ hw3,
                             const float* __restrict__ hw4, const float* __restrict__ hw5,
                             float* __restrict__ ws) {
    int i = blockIdx.x * 256 + threadIdx.x;
    if (i < 16000) { int k = i >> 7, j = i & 127; ws[i] = (j < 125) ? cw2[k * 125 + j] : 0.0f; }
    if (i < 128)   { ws[16000 + i] = (i < 125) ? cb2[i] : 0.0f; }
    if (i < 256)   { int j = i >> 1, c = i & 1; ws[16128 + i] = (j < 125) ? cw3[j * 2 + c] : 0.0f; }
    if (i < 16384) {
        int m = i >> 12, r = (i >> 6) & 63, c = i & 63;
        const float* w = (m == 0) ? hw2 : ((m == 1) ? hw3 : ((m == 2) ? hw4 : hw5));
        ws[16384 + i] = w[c * 64 + r];   // wT[m][r][c] = w[c][r]
    }
}

__global__ __launch_bounds__(TPB, 2) void pnn_main(
        const float* __restrict__ x,
        const float* __restrict__ cw1, const float* __restrict__ cb1,
        const float* __restrict__ cb3,
        const float* __restrict__ hw1, const float* __restrict__ hb1,
        const float* __restrict__ hw2, const float* __restrict__ hb2,
        const float* __restrict__ hw3, const float* __restrict__ hb3,
        const float* __restrict__ hw4, const float* __restrict__ hb4,
        const float* __restrict__ hw5, const float* __restrict__ hb5,
        const float* __restrict__ hw6,
        const float* __restrict__ S, const float* __restrict__ dt_q,
        const float* __restrict__ dt_p, const float* __restrict__ alpha_p,
        const float* __restrict__ wsf,
        float* __restrict__ out, int nrows) {
    __shared__ float buf[64][TPB];    // private column per thread, no barriers anywhere
    const int tid = threadIdx.x;
    const int row = blockIdx.x * TPB + tid;
    if (row >= nrows) return;

    float4 xv = ((const float4*)x)[row];

    // ---- theta = [x1, x2 + coupling(x1)] ----
    float c0, c1;
    coupling_net(xv.x, xv.y, cw1, cb1, wsf, cb3, c0, c1);
    float th0 = xv.x, th1 = xv.y, th2 = xv.z + c0, th3 = xv.w + c1;

    float z[64];

    // ---- H forward L1: z1 = theta @ hw1 + hb1, relu ----
    load64(z, hb1);
    {
        float tin[4] = {th0, th1, th2, th3};
#pragma unroll
        for (int k = 0; k < 4; ++k) {
            float ak = tin[k];
            const float4* w4 = (const float4*)(hw1 + (k << 6));
#pragma unroll
            for (int q = 0; q < 16; ++q) {
                float4 w = w4[q];
                z[4*q+0] = fmaf(ak, w.x, z[4*q+0]);
                z[4*q+1] = fmaf(ak, w.y, z[4*q+1]);
                z[4*q+2] = fmaf(ak, w.z, z[4*q+2]);
                z[4*q+3] = fmaf(ak, w.w, z[4*q+3]);
            }
        }
    }
    unsigned m1lo = 0, m1hi = 0;
#pragma unroll
    for (int j = 0; j < 64; ++j) {
        bool p = z[j] > 0.0f;
        unsigned bit = p ? 1u : 0u;
        if (j < 32) m1lo |= bit << j; else m1hi |= bit << (j - 32);
        buf[j][tid] = p ? z[j] : 0.0f;
    }

    // ---- L2: relu ----
    load64(z, hb2);
    mv64(z, hw2, buf, tid);
    unsigned m2lo = 0, m2hi = 0;
#pragma unroll
    for (int j = 0; j < 64; ++j) {
        bool p = z[j] > 0.0f;
        unsigned bit = p ? 1u : 0u;
        if (j < 32) m2lo |= bit << j; else m2hi |= bit << (j - 32);
        buf[j][tid] = p ? z[j] : 0.0f;
    }

    // ---- L3: tanh (keep t3 in regs for backward) ----
    load64(z, hb3);
    mv64(z, hw3, buf, tid);
    float t3s[64];
#pragma unroll
    for (int j = 0; j < 64; ++j) { t3s[j] = fast_tanh(z[j]); buf[j][tid] = t3s[j]; }

    // ---- L4: tanh (keep t4) ----
    load64(z, hb4);
    mv64(z, hw4, buf, tid);
    float t4s[64];
#pragma unroll
    for (int j = 0; j < 64; ++j) { t4s[j] = fast_tanh(z[j]); buf[j][tid] = t4s[j]; }

    // ---- L5: g5 = hw6 * (1 - tanh(z5)^2) directly ----
    load64(z, hb5);
    mv64(z, hw5, buf, tid);
#pragma unroll
    for (int j = 0; j < 64; ++j) {
        float t5 = fast_tanh(z[j]);
        buf[j][tid] = hw6[j] * fmaf(-t5, t5, 1.0f);
    }

    const float* hw2T = wsf + 16384;
    const float* hw3T = hw2T + 4096;
    const float* hw4T = hw3T + 4096;
    const float* hw5T = hw4T + 4096;

    // ---- B54: g4 = (g5 @ hw5T) * (1 - t4^2) ----
    zero64(z);
    mv64(z, hw5T, buf, tid);
#pragma unroll
    for (int j = 0; j < 64; ++j) buf[j][tid] = z[j] * fmaf(-t4s[j], t4s[j], 1.0f);

    // ---- B43: g3 = (g4 @ hw4T) * (1 - t3^2) ----
    zero64(z);
    mv64(z, hw4T, buf, tid);
#pragma unroll
    for (int j = 0; j < 64; ++j) buf[j][tid] = z[j] * fmaf(-t3s[j], t3s[j], 1.0f);

    // ---- B32: g2 = (g3 @ hw3T) * relu'(z2) ----
    zero64(z);
    mv64(z, hw3T, buf, tid);
#pragma unroll
    for (int j = 0; j < 64; ++j) {
        bool p = (j < 32) ? ((m2lo >> j) & 1u) : ((m2hi >> (j - 32)) & 1u);
        buf[j][tid] = p ? z[j] : 0.0f;
    }

    // ---- B21 + dH: g1 = (g2 @ hw2T) * relu'(z1);  dH = g1 @ hw1T ----
    zero64(z);
    mv64(z, hw2T, buf, tid);
    float dH0 = 0, dH1 = 0, dH2 = 0, dH3 = 0;
#pragma unroll
    for (int j = 0; j < 64; ++j) {
        bool p = (j < 32) ? ((m1lo >> j) & 1u) : ((m1hi >> (j - 32)) & 1u);
        float g = p ? z[j] : 0.0f;
        dH0 = fmaf(g, hw1[j],       dH0);
        dH1 = fmaf(g, hw1[64 + j],  dH1);
        dH2 = fmaf(g, hw1[128 + j], dH2);
        dH3 = fmaf(g, hw1[192 + j], dH3);
    }

    // ---- epilogue: symplectic-ish update + inverse coupling ----
    float s01 = S[1] - S[4],  s02 = S[2]  - S[8],  s03 = S[3]  - S[12];
    float s10 = -s01,         s12 = S[6]  - S[9],  s13 = S[7]  - S[13];
    float s23 = S[11] - S[14];
    float s32 = -s23;

    float al = alpha_p[0], dq = dt_q[0], dp = dt_p[0];
    // (theta @ Ssk.T)[:,i] = sum_j th_j * sk[i][j]
    float r10 = th1 * s01 + th2 * s02 + th3 * s03;
    float r11 = th0 * s10 + th2 * s12 + th3 * s13;
    // (theta @ Ssk)[:,2+i] = sum_j th_j * sk[j][2+i]
    float r20 = th0 * s02 + th1 * s12 + th3 * s32;
    float r21 = th0 * s03 + th1 * s13 + th2 * s23;

    float dz10 = dH2 * dq + al * r10;
    float dz11 = dH3 * dq + al * r11;
    float dz20 = -dH0 * dp + al * r20;
    float dz21 = -dH1 * dp + al * r21;

    float p0 = th0 + 0.1f * dz10;
    float p1 = th1 + 0.1f * dz11;
    float p2 = th2 + 0.1f * dz20;
    float p3 = th3 + 0.1f * dz21;

    float d0, d1;
    coupling_net(p0, p1, cw1, cb1, wsf, cb3, d0, d1);

    ((float4*)out)[row] = make_float4(p0, p1, p2 - d0, p3 - d1);
}

extern "C" void kernel_launch(void* const* d_in, const int* in_sizes, int n_in,
                              void* d_out, int out_size, void* d_ws, size_t ws_size,
                              hipStream_t stream) {
    const float* x   = (const float*)d_in[0];
    const float* cw1 = (const float*)d_in[1];
    const float* cb1 = (const float*)d_in[2];
    const float* cw2 = (const float*)d_in[3];
    const float* cb2 = (const float*)d_in[4];
    const float* cw3 = (const float*)d_in[5];
    const float* cb3 = (const float*)d_in[6];
    const float* hw1 = (const float*)d_in[7];
    const float* hb1 = (const float*)d_in[8];
    const float* hw2 = (const float*)d_in[9];
    const float* hb2 = (const float*)d_in[10];
    const float* hw3 = (const float*)d_in[11];
    const float* hb3 = (const float*)d_in[12];
    const float* hw4 = (const float*)d_in[13];
    const float* hb4 = (const float*)d_in[14];
    const float* hw5 = (const float*)d_in[15];
    const float* hb5 = (const float*)d_in[16];
    const float* hw6 = (const float*)d_in[17];
    const float* S   = (const float*)d_in[19];
    const float* dtq = (const float*)d_in[20];
    const float* dtp = (const float*)d_in[21];
    const float* al  = (const float*)d_in[22];
    float* ws  = (float*)d_ws;
    float* out = (float*)d_out;
    int nrows = in_sizes[0] / 4;

    pack_weights<<<64, 256, 0, stream>>>(cw2, cb2, cw3, hw2, hw3, hw4, hw5, ws);
    int grid = (nrows + TPB - 1) / TPB;
    pnn_main<<<grid, TPB, 0, stream>>>(x, cw1, cb1, cb3, hw1, hb1, hw2, hb2, hw3, hb3,
                                       hw4, hb4, hw5, hb5, hw6,
                                       S, dtq, dtp, al, ws, out, nrows);
}